// Round 13
// baseline (303.310 us; speedup 1.0000x reference)
//
#include <hip/hip_runtime.h>
#include <math.h>

typedef __bf16 bf16;
typedef __bf16 bf16x8 __attribute__((ext_vector_type(8)));
typedef __bf16 bf16x4 __attribute__((ext_vector_type(4)));
typedef float f32x4 __attribute__((ext_vector_type(4)));
typedef unsigned int u32;

#define B_DIM 2
#define S_LEN 2048
#define H_DIM 2048
#define NH 16
#define NKV 4
#define HD 128

// async global->LDS, 16B per lane; LDS dest = wave-uniform base (HW adds lane*16)
__device__ __forceinline__ void gl_lds16(const void* g, void* l) {
    __builtin_amdgcn_global_load_lds(
        (const __attribute__((address_space(1))) unsigned int*)g,
        (__attribute__((address_space(3))) unsigned int*)l, 16, 0, 0);
}

__device__ __forceinline__ void bar() {
    asm volatile("" ::: "memory");
    __builtin_amdgcn_s_barrier();
    asm volatile("" ::: "memory");
}

// ---------------- merged cast fp32 -> bf16 for all 5 inputs ----------------
__global__ __launch_bounds__(256) void cast_all(const float* __restrict__ s0,
                                                const float* __restrict__ s1,
                                                const float* __restrict__ s2,
                                                const float* __restrict__ s3,
                                                const float* __restrict__ s4,
                                                bf16* __restrict__ dst) {
    const int i = blockIdx.x * 256 + threadIdx.x;  // f4 index, < 4718592
    const float* src;
    int off;
    if (i < 2097152)      { src = s0; off = 0; }
    else if (i < 3145728) { src = s1; off = 2097152; }
    else if (i < 3407872) { src = s2; off = 3145728; }
    else if (i < 3670016) { src = s3; off = 3407872; }
    else                  { src = s4; off = 3670016; }
    float4 f = ((const float4*)src)[i - off];
    bf16x4 o = { (bf16)f.x, (bf16)f.y, (bf16)f.z, (bf16)f.w };
    *(bf16x4*)(dst + (size_t)i * 4) = o;
}

// ---------------- 256x256 8-phase GEMM (R5-exact schedule, empirical best) ----------------
template <typename OutT>
__global__ __launch_bounds__(512, 2) void gemm256(const bf16* __restrict__ A,
                                                  const bf16* __restrict__ Bt,
                                                  OutT* __restrict__ C,
                                                  int M, int N, int K) {
    __shared__ __align__(16) bf16 smem[65536];  // A: [slot][mh][kb][128][32] at 0; B same at +32768
    const int t = threadIdx.x, lane = t & 63, w = t >> 6;
    const int lr = lane & 15, quad = lane >> 4;
    const int nN = N >> 8;
    const int nwg = gridDim.x, chunk = nwg >> 3;
    const int bid = blockIdx.x;
    const int lid = (bid & 7) * chunk + (bid >> 3);   // XCD-contiguous
    const int m0 = (lid / nN) << 8, n0 = (lid % nN) << 8;
    const int mh_w = w >> 2;            // wave's A half (0/1)
    const int wn = (w & 3) << 6;        // wave's N offset within tile
    const int nh_w = (w & 3) >> 1;      // wave's B half
    const int rb = (w & 1) << 6;        // row offset within B half
    const int nK = K >> 6;              // K-steps of 64

    const int ld0 = w * 2;
    const int lrow = lane >> 2;                        // 0..15
    const int csrc = (lane & 3) ^ ((lane >> 3) & 3);   // source col8 involution (2-bit)
    const int swz = (lr >> 1) & 3;                     // read-side involution (2-bit)

    auto stA = [&](int ts, int mh) {
        if (ts < nK) {
            bf16* db = smem + (ts & 1) * 16384 + mh * 8192;
            const bf16* sp = A + (size_t)(m0 + mh * 128) * K + ts * 64;
#pragma unroll
            for (int i = 0; i < 2; i++) {
                const int ldi = ld0 + i, kb = ldi >> 3, rg = ldi & 7;
                gl_lds16(sp + (size_t)(rg * 16 + lrow) * K + kb * 32 + csrc * 8,
                         db + kb * 4096 + rg * 512);
            }
        }
    };
    auto stB = [&](int ts, int nh) {
        if (ts < nK) {
            bf16* db = smem + 32768 + (ts & 1) * 16384 + nh * 8192;
            const bf16* sp = Bt + (size_t)(n0 + nh * 128) * K + ts * 64;
#pragma unroll
            for (int i = 0; i < 2; i++) {
                const int ldi = ld0 + i, kb = ldi >> 3, rg = ldi & 7;
                gl_lds16(sp + (size_t)(rg * 16 + lrow) * K + kb * 32 + csrc * 8,
                         db + kb * 4096 + rg * 512);
            }
        }
    };

    f32x4 acc[8][4];
#pragma unroll
    for (int i = 0; i < 8; i++)
#pragma unroll
        for (int j = 0; j < 4; j++) acc[i][j] = (f32x4){0.f, 0.f, 0.f, 0.f};
    bf16x8 af[8], b0[4], b1[4];  // af[fi*2+ks] current fi-group; b[fj*2+ks]

    auto rdA = [&](int s, int fi0) {
        const bf16* bp = smem + s * 16384 + mh_w * 8192;
#pragma unroll
        for (int f = 0; f < 4; f++)
#pragma unroll
            for (int ks = 0; ks < 2; ks++)
                af[f * 2 + ks] = *(const bf16x8*)(bp + ks * 4096 +
                                                  ((fi0 + f) * 16 + lr) * 32 + (quad ^ swz) * 8);
    };
    auto rdB = [&](int s, int fj0, bf16x8* dst) {
        const bf16* bp = smem + 32768 + s * 16384 + nh_w * 8192;
#pragma unroll
        for (int f = 0; f < 2; f++)
#pragma unroll
            for (int ks = 0; ks < 2; ks++)
                dst[f * 2 + ks] = *(const bf16x8*)(bp + ks * 4096 +
                                                   (rb + (fj0 + f) * 16 + lr) * 32 + (quad ^ swz) * 8);
    };
    auto mm16 = [&](int fi0, int fj0, bf16x8* bb) {  // 16 MFMA = one C-quadrant x K=64
        __builtin_amdgcn_s_setprio(1);
#pragma unroll
        for (int f = 0; f < 4; f++)
#pragma unroll
            for (int g = 0; g < 2; g++)
#pragma unroll
                for (int ks = 0; ks < 2; ks++)
                    acc[fi0 + f][fj0 + g] = __builtin_amdgcn_mfma_f32_16x16x32_bf16(
                        af[f * 2 + ks], bb[g * 2 + ks], acc[fi0 + f][fj0 + g], 0, 0, 0);
        __builtin_amdgcn_s_setprio(0);
    };

    // prologue: stage H(0) fully + A(1,mh0); wait all but last half-tile
    stA(0, 0); stA(0, 1); stB(0, 0); stB(0, 1); stA(1, 0);
    asm volatile("s_waitcnt vmcnt(2)" ::: "memory");
    bar();

    for (int ts = 0; ts < nK; ++ts) {
        const int s = ts & 1;
        // phase q0: A-frags fi0-3, B-frags fj0-1
        rdA(s, 0); rdB(s, 0, b0);
        stA(ts + 1, 1);
        bar();
        mm16(0, 0, b0);
        bar();
        // phase q1: B-frags fj2-3
        rdB(s, 2, b1);
        stB(ts + 1, 0);
        bar();
        mm16(0, 2, b1);
        bar();
        // phase q2: A-frags fi4-7
        rdA(s, 4);
        stB(ts + 1, 1);
        bar();
        mm16(4, 2, b1);
        bar();
        // phase q3: B-frags fj0-1 (re-read)
        rdB(s, 0, b0);
        stA(ts + 2, 0);
        bar();
        mm16(4, 0, b0);
        if (ts + 2 < nK) asm volatile("s_waitcnt vmcnt(2)" ::: "memory");
        else             asm volatile("s_waitcnt vmcnt(0)" ::: "memory");
        bar();
    }
    // epilogue
#pragma unroll
    for (int fi = 0; fi < 8; fi++) {
        const int m = m0 + mh_w * 128 + fi * 16 + quad * 4;
#pragma unroll
        for (int fj = 0; fj < 4; fj++) {
            const int n = n0 + wn + fj * 16 + lr;
#pragma unroll
            for (int r = 0; r < 4; r++)
                C[(size_t)(m + r) * N + n] = (OutT)acc[fi][fj][r];
        }
    }
}

// ---------------- 256x128 full-fill GEMM for the projection (f32 out) ----------------
// grid = 16x16 = 256 blocks = exactly 1/CU (proj at 256^2 was 128 blocks = 50% fill).
__global__ __launch_bounds__(512, 1) void gemm_pn(const bf16* __restrict__ A,
                                                  const bf16* __restrict__ Bt,
                                                  float* __restrict__ C,
                                                  int M, int N, int K) {
    __shared__ __align__(16) bf16 smem[49152];  // A: [slot][mh][kb][128][32] at 0; B: [slot][kb][128][32] at +32768
    const int t = threadIdx.x, lane = t & 63, w = t >> 6;
    const int lr = lane & 15, quad = lane >> 4;
    const int nN = N >> 7;
    const int nwg = gridDim.x, chunk = nwg >> 3;
    const int bid = blockIdx.x;
    const int lid = (bid & 7) * chunk + (bid >> 3);   // XCD-contiguous
    const int m0 = (lid / nN) << 8, n0 = (lid % nN) << 7;
    const int mh_w = w >> 2;            // wave's A half (0/1)
    const int wn = (w & 3) << 5;        // wave's 32-wide N slice within the 128 tile
    const int nK = K >> 6;              // K-steps of 64

    const int ld0 = w * 2;
    const int lrow = lane >> 2;                        // 0..15
    const int csrc = (lane & 3) ^ ((lane >> 3) & 3);   // source col8 involution (2-bit)
    const int swz = (lr >> 1) & 3;                     // read-side involution (2-bit)

    auto stA = [&](int ts, int mh) {
        if (ts < nK) {
            bf16* db = smem + (ts & 1) * 16384 + mh * 8192;
            const bf16* sp = A + (size_t)(m0 + mh * 128) * K + ts * 64;
#pragma unroll
            for (int i = 0; i < 2; i++) {
                const int ldi = ld0 + i, kb = ldi >> 3, rg = ldi & 7;
                gl_lds16(sp + (size_t)(rg * 16 + lrow) * K + kb * 32 + csrc * 8,
                         db + kb * 4096 + rg * 512);
            }
        }
    };
    auto stB1 = [&](int ts) {  // whole 128-row B tile (16 KB)
        if (ts < nK) {
            bf16* db = smem + 32768 + (ts & 1) * 8192;
            const bf16* sp = Bt + (size_t)n0 * K + ts * 64;
#pragma unroll
            for (int i = 0; i < 2; i++) {
                const int ldi = ld0 + i, kb = ldi >> 3, rg = ldi & 7;
                gl_lds16(sp + (size_t)(rg * 16 + lrow) * K + kb * 32 + csrc * 8,
                         db + kb * 4096 + rg * 512);
            }
        }
    };

    f32x4 acc[8][2];
#pragma unroll
    for (int i = 0; i < 8; i++)
#pragma unroll
        for (int j = 0; j < 2; j++) acc[i][j] = (f32x4){0.f, 0.f, 0.f, 0.f};
    bf16x8 af[8], bf1[4];

    auto rdA = [&](int s, int fi0) {
        const bf16* bp = smem + s * 16384 + mh_w * 8192;
#pragma unroll
        for (int f = 0; f < 4; f++)
#pragma unroll
            for (int ks = 0; ks < 2; ks++)
                af[f * 2 + ks] = *(const bf16x8*)(bp + ks * 4096 +
                                                  ((fi0 + f) * 16 + lr) * 32 + (quad ^ swz) * 8);
    };
    auto rdB1 = [&](int s) {
        const bf16* bp = smem + 32768 + s * 8192;
#pragma unroll
        for (int f = 0; f < 2; f++)
#pragma unroll
            for (int ks = 0; ks < 2; ks++)
                bf1[f * 2 + ks] = *(const bf16x8*)(bp + ks * 4096 +
                                                   (wn + f * 16 + lr) * 32 + (quad ^ swz) * 8);
    };
    auto mm8 = [&](int fi0, int ks) {  // 8 independent MFMA (each acc touched once)
        __builtin_amdgcn_s_setprio(1);
#pragma unroll
        for (int f = 0; f < 4; f++)
#pragma unroll
            for (int g = 0; g < 2; g++)
                acc[fi0 + f][g] = __builtin_amdgcn_mfma_f32_16x16x32_bf16(
                    af[f * 2 + ks], bf1[g * 2 + ks], acc[fi0 + f][g], 0, 0, 0);
        __builtin_amdgcn_s_setprio(0);
    };

    // prologue: stage step 0, drain
    stA(0, 0); stA(0, 1); stB1(0);
    asm volatile("s_waitcnt vmcnt(0)" ::: "memory");
    bar();

    for (int ts = 0; ts < nK; ++ts) {
        const int s = ts & 1;
        // q0: A-frags fi0-3 + all B-frags ; stage A(t+1,0)
        rdA(s, 0); rdB1(s);
        stA(ts + 1, 0);
        bar();
        mm8(0, 0);
        bar();
        // q1: stage A(t+1,1) + B(t+1)
        stA(ts + 1, 1);
        stB1(ts + 1);
        bar();
        mm8(0, 1);
        bar();
        // q2: A-frags fi4-7
        rdA(s, 4);
        bar();
        mm8(4, 0);
        bar();
        // q3: register-only MFMA, then drain staged loads (issued >=2 phases ago)
        mm8(4, 1);
        asm volatile("s_waitcnt vmcnt(0)" ::: "memory");
        bar();
    }
    // epilogue: f32 stores, lanes lr contiguous in n
#pragma unroll
    for (int fi = 0; fi < 8; fi++) {
        const int m = m0 + mh_w * 128 + fi * 16 + quad * 4;
#pragma unroll
        for (int fj = 0; fj < 2; fj++) {
            const int n = n0 + wn + fj * 16 + lr;
#pragma unroll
            for (int r = 0; r < 4; r++)
                C[(size_t)(m + r) * N + n] = acc[fi][fj][r];
        }
    }
}

// ---------------- RoPE + RMSNorm; K and V written in MFMA-tiled layouts ----------------
// K: [(b,kvh)][dchunk=d>>3 (16)][s (2048)][d&7 (8)]
// V (sigma-permuted for flash's shuffle-free P^T fragments):
//   [(b,kvh)][gi = (s>>5)*4 + ((s&15)>>2) (256)][d (128)][el = ((s>>4)&1)*4 + (s&3) (8)]
__global__ __launch_bounds__(256) void rope_rms(const bf16* __restrict__ qkv,
                                                const float* __restrict__ qw,
                                                const float* __restrict__ kw,
                                                bf16* __restrict__ qb,
                                                bf16* __restrict__ kb,
                                                bf16* __restrict__ vt) {
    const int tok = blockIdx.x;
    const int b = tok >> 11, s = tok & (S_LEN - 1);
    const int lane = threadIdx.x & 63, w = threadIdx.x >> 6;
    const bf16* row = qkv + (size_t)tok * 3072;
    const float inv = expf(-(float)lane * (9.210340371976184f / 64.f));
    const float ang = (float)s * inv;
    float s_, c_;
    sincosf(ang, &s_, &c_);
    const float wq1 = qw[lane], wq2 = qw[lane + 64];
    const float wk1 = kw[lane], wk2 = kw[lane + 64];
    for (int u = w; u < 24; u += 4) {
        if (u < 16) {  // Q head: row-major [b,h][s][d]
            const float x1 = (float)row[u * 128 + lane], x2 = (float)row[u * 128 + 64 + lane];
            float y1 = x1 * c_ - x2 * s_;
            float y2 = x2 * c_ + x1 * s_;
            float ss = y1 * y1 + y2 * y2;
#pragma unroll
            for (int m = 1; m < 64; m <<= 1) ss += __shfl_xor(ss, m);
            const float r = rsqrtf(ss * (1.f / 128.f) + 1e-6f);
            size_t o = ((size_t)(b * NH + u) * S_LEN + s) * HD;
            qb[o + lane]      = (bf16)(y1 * r * wq1);
            qb[o + 64 + lane] = (bf16)(y2 * r * wq2);
        } else if (u < 20) {  // K head: tiled
            const int kh = u - 16;
            const float x1 = (float)row[2048 + kh * 128 + lane], x2 = (float)row[2048 + kh * 128 + 64 + lane];
            float y1 = x1 * c_ - x2 * s_;
            float y2 = x2 * c_ + x1 * s_;
            float ss = y1 * y1 + y2 * y2;
#pragma unroll
            for (int m = 1; m < 64; m <<= 1) ss += __shfl_xor(ss, m);
            const float r = rsqrtf(ss * (1.f / 128.f) + 1e-6f);
            size_t base = (size_t)(b * NKV + kh) * 16 * 16384;
            kb[base + (size_t)(lane >> 3) * 16384 + s * 8 + (lane & 7)]       = (bf16)(y1 * r * wk1);
            kb[base + (size_t)(8 + (lane >> 3)) * 16384 + s * 8 + (lane & 7)] = (bf16)(y2 * r * wk2);
        } else {  // V head: sigma-permuted tiled cast
            const int vh = u - 20;
            const float x1 = (float)row[2560 + vh * 128 + lane], x2 = (float)row[2560 + vh * 128 + 64 + lane];
            const int m = s & 31;
            const int gi = (s >> 5) * 4 + ((m & 15) >> 2);
            const int el = ((m >> 4) << 2) | (m & 3);
            size_t base = ((size_t)(b * NKV + vh) * 256 + gi) * 1024 + el;
            vt[base + (size_t)lane * 8]        = (bf16)x1;
            vt[base + (size_t)(lane + 64) * 8] = (bf16)x2;
        }
    }
}

// ---------------- flash attention v10 (causal, GQA, split-KV, 8-wave blocks) ----------------
// R11 counters: MFMA 21 / VALU ~30 / LDS ~33 / HBM 13, Occupancy 15% -> latency-
// bound, occupancy-starved. v10: same BM=128 tile and identical per-tile pipeline,
// but 8 waves x 16 rows (512 thr) instead of 4 x 32 -> 16 waves/CU (2 blocks),
// doubling TLP. Per-wave state halves (VGPR ~110 < 128 cap for 4 waves/SIMD).
// No sync-structure change: same single __syncthreads per tile, same split-KV
// work list, same T12 cvt_pk softmax + T5 setprio.
// (R12 submission of this exact kernel died to a container-level failure; audit
// found no crash/hang mechanism — resubmitting per the R6->R7 flake precedent.)
__global__ __launch_bounds__(512, 4) void flash(const bf16* __restrict__ qg,
                                                const bf16* __restrict__ kg,
                                                const bf16* __restrict__ vg,
                                                bf16* __restrict__ attn,
                                                float* __restrict__ part_o,
                                                float* __restrict__ part_l) {
    // work list, descending tile count (9:20, 8:18, 15c:16, 7:16, 14c:15, ...)
    static const unsigned char QT[22] = {9,8,15,15,7,14,14,13,13,6,12,12,11,11,5,10,10,4,3,2,1,0};
    static const unsigned char CK[22] = {2,2,0,1,2,0,1,0,1,2,0,1,0,1,2,0,1,2,2,2,2,2};
    const int idx = blockIdx.x;
    const int g = idx >> 5, hb = idx & 31;
    const int qt = QT[g], ck = CK[g];
    const int h = hb & 15, b = hb >> 4;
    const int kvh = h >> 2;
    const int ktBeg = (ck == 1) ? (qt + 1) : 0;
    const int ktEnd = (ck == 0) ? (qt + 1) : (2 * qt + 2);
    const bf16* qh = qg + (size_t)(b * NH + h) * S_LEN * HD;
    const bf16* kh = kg + (size_t)(b * NKV + kvh) * (16 * 16384);
    const bf16* vh = vg + (size_t)(b * NKV + kvh) * (256 * 1024);
    __shared__ __align__(16) bf16 Ks[2][16 * 512];  // [buf][dchunk16][key64][8]  32 KB
    __shared__ __align__(16) bf16 Vs[2][8 * 1024];  // [buf][chunk8][d128][el8]   32 KB
    const int t = threadIdx.x, lane = t & 63, w = t >> 6, lr = lane & 15, quad = lane >> 4;
    const int row0 = qt * 128 + w * 16;             // this wave's 16 q-rows
    bf16x8 qf[4];
#pragma unroll
    for (int c = 0; c < 4; c++)
        qf[c] = *(const bf16x8*)(qh + (size_t)(row0 + lr) * HD + c * 32 + quad * 8);
    f32x4 o[8];
    f32x4 lacc = (f32x4){0.f, 0.f, 0.f, 0.f};
#pragma unroll
    for (int j = 0; j < 8; j++) o[j] = (f32x4){0.f, 0.f, 0.f, 0.f};
    const bf16 one = (bf16)1.0f;
    const bf16x8 ones8 = {one, one, one, one, one, one, one, one};
    const float C1 = 0.12751744f;    // (1/sqrt(128)) * log2(e)
    const float C2 = -17.3123405f;   // -12 * log2(e)   (fixed max M=12 > sqrt(128))

    // loop-invariant staging bases: K 2 dchunks/wave, V 1 chunk/wave (x8 waves)
    const bf16* kp[2];
#pragma unroll
    for (int i = 0; i < 2; i++) kp[i] = kh + (size_t)(w * 2 + i) * 16384 + lane * 8;
    const bf16* vp = vh + (size_t)w * 1024 + lane * 8;

    auto stage = [&](int kt_, int bi) {  // K+V tile kt_ -> buffers [bi]
        const size_t kb8 = (size_t)kt_ * 512;
#pragma unroll
        for (int i = 0; i < 2; i++)
            gl_lds16(kp[i] + kb8, &Ks[bi][(w * 2 + i) * 512]);
        const size_t vb = (size_t)kt_ * 8192;
        gl_lds16(vp + vb, &Vs[bi][w * 1024]);
        gl_lds16(vp + vb + 512, &Vs[bi][w * 1024 + 512]);
    };

    stage(ktBeg, 0);
    __syncthreads();
    int cur = 0;

    for (int kt = ktBeg; kt < ktEnd; ++kt) {
        const int kbase = kt * 64;
        if (kt + 1 < ktEnd) stage(kt + 1, cur ^ 1);  // prefetch; lands during this tile's compute
        // ---- QK^T (swapped): sacc[n] = S^T tile, col=lr=qrow, row=quad*4+r=key ----
        f32x4 sacc[4];
#pragma unroll
        for (int n = 0; n < 4; n++) sacc[n] = (f32x4){0.f, 0.f, 0.f, 0.f};
        __builtin_amdgcn_s_setprio(1);
#pragma unroll
        for (int c = 0; c < 4; c++)
#pragma unroll
            for (int n = 0; n < 4; n++) {
                bf16x8 kf = *(const bf16x8*)&Ks[cur][(c * 4 + quad) * 512 + (n * 16 + lr) * 8];
                sacc[n] = __builtin_amdgcn_mfma_f32_16x16x32_bf16(kf, qf[c], sacc[n], 0, 0, 0);
            }
        __builtin_amdgcn_s_setprio(0);
        // ---- fixed-max softmax -> P^T B-fragments via v_cvt_pk_bf16_f32 (T12) ----
        const bool diag = (kt >= 2 * qt);
        u32 pw[8];  // [(n>>1)*4 + (n&1)*2 + j] — compile-time indices
        {
            const int qrow = row0 + lr;
#pragma unroll
            for (int n = 0; n < 4; n++) {
                float e0, e1, e2, e3;
                {
                    float ev0 = exp2f(fmaf(sacc[n][0], C1, C2));
                    float ev1 = exp2f(fmaf(sacc[n][1], C1, C2));
                    float ev2 = exp2f(fmaf(sacc[n][2], C1, C2));
                    float ev3 = exp2f(fmaf(sacc[n][3], C1, C2));
                    if (diag) {
                        const int key = kbase + n * 16 + quad * 4;
                        ev0 = (key + 0 <= qrow) ? ev0 : 0.f;
                        ev1 = (key + 1 <= qrow) ? ev1 : 0.f;
                        ev2 = (key + 2 <= qrow) ? ev2 : 0.f;
                        ev3 = (key + 3 <= qrow) ? ev3 : 0.f;
                    }
                    e0 = ev0; e1 = ev1; e2 = ev2; e3 = ev3;
                }
                asm("v_cvt_pk_bf16_f32 %0, %1, %2"
                    : "=v"(pw[(n >> 1) * 4 + (n & 1) * 2 + 0]) : "v"(e0), "v"(e1));
                asm("v_cvt_pk_bf16_f32 %0, %1, %2"
                    : "=v"(pw[(n >> 1) * 4 + (n & 1) * 2 + 1]) : "v"(e2), "v"(e3));
            }
        }
        // ---- PV: O^T += V^T * P^T ; l via all-ones A-frag ----
        __builtin_amdgcn_s_setprio(1);
#pragma unroll
        for (int k2 = 0; k2 < 2; k2++) {
            const bf16x8 p0 = *(const bf16x8*)&pw[k2 * 4];
#pragma unroll
            for (int j = 0; j < 8; j++) {
                bf16x8 vf = *(const bf16x8*)&Vs[cur][(k2 * 4 + quad) * 1024 + (j * 16 + lr) * 8];
                o[j] = __builtin_amdgcn_mfma_f32_16x16x32_bf16(vf, p0, o[j], 0, 0, 0);
            }
            lacc = __builtin_amdgcn_mfma_f32_16x16x32_bf16(ones8, p0, lacc, 0, 0, 0);
        }
        __builtin_amdgcn_s_setprio(0);
        __syncthreads();  // drains stage(kt+1) (issued a full tile ago) + publishes buffers
        cur ^= 1;
    }
    // epilogue
    if (ck == 2) {  // direct: normalize, bf16x4 stores
        const float inv = 1.0f / lacc[0];
        const int qrow = row0 + lr;
        bf16* dst = attn + ((size_t)(b * S_LEN) + qrow) * (NH * HD) + h * HD + quad * 4;
#pragma unroll
        for (int j = 0; j < 8; j++) {
            bf16x4 st = { (bf16)(o[j][0] * inv), (bf16)(o[j][1] * inv),
                          (bf16)(o[j][2] * inv), (bf16)(o[j][3] * inv) };
            *(bf16x4*)(dst + j * 16) = st;
        }
    } else {  // partial: unnormalized f32 O + l
        const int slot = ((b * NH + h) * 6 + (qt - 10)) * 2 + ck;
        float* po = part_o + (size_t)slot * 16384;
        const int row = w * 16 + lr;
#pragma unroll
        for (int j = 0; j < 8; j++) {
            float4 st = { o[j][0], o[j][1], o[j][2], o[j][3] };
            *(float4*)(po + row * 128 + j * 16 + quad * 4) = st;
        }
        if (quad == 0) part_l[slot * 128 + row] = lacc[0];
    }
}

// ---------------- combine split-KV partials, normalize, write attn ----------------
// grid = 192 blocks: one per (b,h,qt in 10..15); 256 threads.
__global__ __launch_bounds__(256) void reduce_attn(const float* __restrict__ part_o,
                                                   const float* __restrict__ part_l,
                                                   bf16* __restrict__ attn) {
    const int blk = blockIdx.x;              // = (b*16+h)*6 + (qt-10)
    const int qt = (blk % 6) + 10;
    const int h = (blk / 6) & 15, b = blk / 96;
    const float* p0 = part_o + (size_t)(blk * 2 + 0) * 16384;
    const float* p1 = part_o + (size_t)(blk * 2 + 1) * 16384;
    const float* l0 = part_l + (blk * 2 + 0) * 128;
    const float* l1 = part_l + (blk * 2 + 1) * 128;
    const int t = threadIdx.x;
#pragma unroll
    for (int it = 0; it < 16; it++) {
        const int idx = it * 256 + t;        // f32x4 id, 4096 total
        const int row = idx >> 5, d4 = idx & 31;
        float4 a = ((const float4*)p0)[idx];
        float4 c = ((const float4*)p1)[idx];
        const float inv = 1.0f / (l0[row] + l1[row]);
        bf16x4 ov = { (bf16)((a.x + c.x) * inv), (bf16)((a.y + c.y) * inv),
                      (bf16)((a.z + c.z) * inv), (bf16)((a.w + c.w) * inv) };
        *(bf16x4*)(attn + ((size_t)(b * S_LEN) + qt * 128 + row) * (NH * HD) + h * HD + d4 * 4) = ov;
    }
}

extern "C" void kernel_launch(void* const* d_in, const int* in_sizes, int n_in,
                              void* d_out, int out_size, void* d_ws, size_t ws_size,
                              hipStream_t stream) {
    (void)in_sizes; (void)n_in; (void)out_size; (void)ws_size;
    const float* hs  = (const float*)d_in[0];
    const float* wq  = (const float*)d_in[1];
    const float* wk  = (const float*)d_in[2];
    const float* wv  = (const float*)d_in[3];
    const float* wo  = (const float*)d_in[4];
    const float* qnw = (const float*)d_in[5];
    const float* knw = (const float*)d_in[6];
    float* out = (float*)d_out;

    char* ws = (char*)d_ws;
    size_t off = 0;
    auto alloc = [&](size_t bytes) {
        void* p = ws + off;
        off += (bytes + 255) & ~(size_t)255;
        return p;
    };
    // NOTE: hs_bf / wqkv_bf / wo_bf must stay contiguous (cast_all writes them
    // as one flat region).
    bf16* hs_bf   = (bf16*)alloc((size_t)4096 * 2048 * 2);
    bf16* wqkv_bf = (bf16*)alloc((size_t)3072 * 2048 * 2);
    bf16* wo_bf   = (bf16*)alloc((size_t)2048 * 2048 * 2);
    bf16* qkv_bf  = (bf16*)alloc((size_t)4096 * 3072 * 2);
    bf16* q_bf    = (bf16*)alloc((size_t)B_DIM * NH * S_LEN * HD * 2);
    bf16* k_bf    = (bf16*)alloc((size_t)B_DIM * NKV * S_LEN * HD * 2);
    bf16* vt_bf   = (bf16*)alloc((size_t)B_DIM * NKV * S_LEN * HD * 2);
    bf16* at_bf   = (bf16*)alloc((size_t)4096 * 2048 * 2);

    // split-KV partials alias the hs_bf+wqkv_bf region (29.36 MB, free once the
    // QKV GEMM has consumed it; flash runs strictly after). 384 slots:
    // part_o 384*16384*4 = 25.17 MB, part_l 384*128*4 = 196 KB.
    float* part_o = (float*)hs_bf;
    float* part_l = (float*)((char*)hs_bf + (size_t)384 * 16384 * 4);

    cast_all<<<18432, 256, 0, stream>>>(hs, wq, wk, wv, wo, hs_bf);
    gemm256<bf16><<<dim3(192), 512, 0, stream>>>(hs_bf, wqkv_bf, qkv_bf, 4096, 3072, 2048);
    rope_rms<<<4096, 256, 0, stream>>>(qkv_bf, qnw, knw, q_bf, k_bf, vt_bf);
    flash<<<dim3(704), 512, 0, stream>>>(q_bf, k_bf, vt_bf, at_bf, part_o, part_l);
    reduce_attn<<<dim3(192), 256, 0, stream>>>(part_o, part_l, at_bf);
    gemm_pn<<<dim3(256), 512, 0, stream>>>(at_bf, wo_bf, out, 4096, 2048, 2048);
}

// Round 14
// 295.380 us; speedup vs baseline: 1.0268x; 1.0268x over previous
//
#include <hip/hip_runtime.h>
#include <math.h>

typedef __bf16 bf16;
typedef __bf16 bf16x8 __attribute__((ext_vector_type(8)));
typedef __bf16 bf16x4 __attribute__((ext_vector_type(4)));
typedef float f32x4 __attribute__((ext_vector_type(4)));
typedef unsigned int u32;

#define B_DIM 2
#define S_LEN 2048
#define H_DIM 2048
#define NH 16
#define NKV 4
#define HD 128

// async global->LDS, 16B per lane; LDS dest = wave-uniform base (HW adds lane*16)
__device__ __forceinline__ void gl_lds16(const void* g, void* l) {
    __builtin_amdgcn_global_load_lds(
        (const __attribute__((address_space(1))) unsigned int*)g,
        (__attribute__((address_space(3))) unsigned int*)l, 16, 0, 0);
}

__device__ __forceinline__ void bar() {
    asm volatile("" ::: "memory");
    __builtin_amdgcn_s_barrier();
    asm volatile("" ::: "memory");
}

// ---------------- merged cast fp32 -> bf16 for all 5 inputs ----------------
__global__ __launch_bounds__(256) void cast_all(const float* __restrict__ s0,
                                                const float* __restrict__ s1,
                                                const float* __restrict__ s2,
                                                const float* __restrict__ s3,
                                                const float* __restrict__ s4,
                                                bf16* __restrict__ dst) {
    const int i = blockIdx.x * 256 + threadIdx.x;  // f4 index, < 4718592
    const float* src;
    int off;
    if (i < 2097152)      { src = s0; off = 0; }
    else if (i < 3145728) { src = s1; off = 2097152; }
    else if (i < 3407872) { src = s2; off = 3145728; }
    else if (i < 3670016) { src = s3; off = 3407872; }
    else                  { src = s4; off = 3670016; }
    float4 f = ((const float4*)src)[i - off];
    bf16x4 o = { (bf16)f.x, (bf16)f.y, (bf16)f.z, (bf16)f.w };
    *(bf16x4*)(dst + (size_t)i * 4) = o;
}

// ---------------- 256x192 full-fill QKV GEMM: C[M][N] = A[M][K] * Bt[N][K]^T ----------------
// R13 finding: gemm256 (256^2, 128KB LDS, 1 block/CU) at QKV's 192-block grid
// left 64 CUs idle (75% fill). BM=256 x BN=192 -> grid 16x16 = 256 = 1 block/CU,
// 100% fill. LDS 112KB: A [slot][mh][kb][128][32] (64KB) + B [slot][sub3][kb][64][32]
// (48KB). Same 2-bit XOR swizzle both sides; R5-exact 4-phase schedule semantics:
// 7 stage-loads/K-step, vmcnt(2)@q3 drains exactly step-t+1's 7 loads (youngest
// issued @q2), B[s^1] staged with zero readers, A[s][mh0] staged after its last
// consuming mm16 + barrier.
__global__ __launch_bounds__(512, 2) void gemm_qkv(const bf16* __restrict__ A,
                                                   const bf16* __restrict__ Bt,
                                                   bf16* __restrict__ C,
                                                   int M, int N, int K) {
    __shared__ __align__(16) bf16 smem[57344];  // A at 0 (32768 elems); B at +32768 (24576 elems)
    const int t = threadIdx.x, lane = t & 63, w = t >> 6;
    const int lr = lane & 15, quad = lane >> 4;
    const int nN = N / 192;
    const int nwg = gridDim.x, chunk = nwg >> 3;
    const int bid = blockIdx.x;
    const int lid = (bid & 7) * chunk + (bid >> 3);   // XCD-contiguous
    const int m0 = (lid / nN) << 8, n0 = (lid % nN) * 192;
    const int mh_w = w >> 2;            // wave's A half (0/1)
    const int wn = (w & 3) * 48;        // wave's N offset within tile (4 x 48)
    const int nK = K >> 6;              // K-steps of 64

    const int ld0 = w * 2;
    const int lrow = lane >> 2;                        // 0..15
    const int csrc = (lane & 3) ^ ((lane >> 3) & 3);   // source col8 involution (2-bit)
    const int swz = (lr >> 1) & 3;                     // read-side involution (2-bit)

    auto stA = [&](int ts, int mh) {
        if (ts < nK) {
            bf16* db = smem + (ts & 1) * 16384 + mh * 8192;
            const bf16* sp = A + (size_t)(m0 + mh * 128) * K + ts * 64;
#pragma unroll
            for (int i = 0; i < 2; i++) {
                const int ldi = ld0 + i, kb = ldi >> 3, rg = ldi & 7;
                gl_lds16(sp + (size_t)(rg * 16 + lrow) * K + kb * 32 + csrc * 8,
                         db + kb * 4096 + rg * 512);
            }
        }
    };
    // B sub-unit (64 rows x 64 K): 8KB = 1 load/wave. Wave w covers kb=w>>2,
    // rows (w&3)*16 + lrow; dest is wave-uniform (HW adds lane*16).
    auto stB = [&](int ts, int sub) {
        if (ts < nK) {
            bf16* db = smem + 32768 + (ts & 1) * 12288 + sub * 4096 +
                       (w >> 2) * 2048 + (w & 3) * 512;
            const bf16* sp = Bt + (size_t)(n0 + sub * 64) * K + ts * 64;
            gl_lds16(sp + (size_t)((w & 3) * 16 + lrow) * K + (w >> 2) * 32 + csrc * 8, db);
        }
    };

    f32x4 acc[8][3];
#pragma unroll
    for (int i = 0; i < 8; i++)
#pragma unroll
        for (int j = 0; j < 3; j++) acc[i][j] = (f32x4){0.f, 0.f, 0.f, 0.f};
    bf16x8 af[8], b0[4], b1[2];  // b0 = frags fj0,fj1; b1 = frag fj2

    auto rdA = [&](int s, int fi0) {
        const bf16* bp = smem + s * 16384 + mh_w * 8192;
#pragma unroll
        for (int f = 0; f < 4; f++)
#pragma unroll
            for (int ks = 0; ks < 2; ks++)
                af[f * 2 + ks] = *(const bf16x8*)(bp + ks * 4096 +
                                                  ((fi0 + f) * 16 + lr) * 32 + (quad ^ swz) * 8);
    };
    auto rdB = [&](int s, int fj0, int nf, bf16x8* dst) {
        const bf16* bp = smem + 32768 + s * 12288;
#pragma unroll
        for (int f = 0; f < 2; f++) {
            if (f >= nf) break;
            const int rowb = wn + (fj0 + f) * 16;      // multiple of 16, < 192
            const int sub = rowb >> 6, r64 = rowb & 63;
#pragma unroll
            for (int ks = 0; ks < 2; ks++)
                dst[f * 2 + ks] = *(const bf16x8*)(bp + sub * 4096 + ks * 2048 +
                                                   (r64 + lr) * 32 + (quad ^ swz) * 8);
        }
    };
    auto mmq = [&](int fi0, int fj0, int nf, bf16x8* bb) {  // nf*8 MFMA
        __builtin_amdgcn_s_setprio(1);
#pragma unroll
        for (int f = 0; f < 4; f++)
#pragma unroll
            for (int g = 0; g < 2; g++) {
                if (g >= nf) break;
#pragma unroll
                for (int ks = 0; ks < 2; ks++)
                    acc[fi0 + f][fj0 + g] = __builtin_amdgcn_mfma_f32_16x16x32_bf16(
                        af[f * 2 + ks], bb[g * 2 + ks], acc[fi0 + f][fj0 + g], 0, 0, 0);
            }
        __builtin_amdgcn_s_setprio(0);
    };

    // prologue: stage tile 0 fully (7 loads) + A(1,mh0) (2); drain all but last stage
    stA(0, 0); stA(0, 1); stB(0, 0); stB(0, 1); stB(0, 2); stA(1, 0);
    asm volatile("s_waitcnt vmcnt(2)" ::: "memory");
    bar();

    for (int ts = 0; ts < nK; ++ts) {
        const int s = ts & 1;
        // q0: A-frags fi0-3, B-frags fj0-1 ; stage A(ts+1,mh1)
        rdA(s, 0); rdB(s, 0, 2, b0);
        stA(ts + 1, 1);
        bar();
        mmq(0, 0, 2, b0);
        bar();
        // q1: B-frag fj2 ; stage B(ts+1) subs 0,1
        rdB(s, 2, 1, b1);
        stB(ts + 1, 0); stB(ts + 1, 1);
        bar();
        mmq(0, 2, 1, b1);
        bar();
        // q2: A-frags fi4-7 ; stage B(ts+1) sub 2
        rdA(s, 4);
        stB(ts + 1, 2);
        bar();
        mmq(4, 2, 1, b1);
        bar();
        // q3: B-frags fj0-1 (re-read) ; stage A(ts+2,mh0)
        rdB(s, 0, 2, b0);
        stA(ts + 2, 0);
        bar();
        mmq(4, 0, 2, b0);
        if (ts + 2 < nK) asm volatile("s_waitcnt vmcnt(2)" ::: "memory");
        else             asm volatile("s_waitcnt vmcnt(0)" ::: "memory");
        bar();
    }
    // epilogue
#pragma unroll
    for (int fi = 0; fi < 8; fi++) {
        const int m = m0 + mh_w * 128 + fi * 16 + quad * 4;
#pragma unroll
        for (int fj = 0; fj < 3; fj++) {
            const int n = n0 + wn + fj * 16 + lr;
#pragma unroll
            for (int r = 0; r < 4; r++)
                C[(size_t)(m + r) * N + n] = (bf16)acc[fi][fj][r];
        }
    }
}

// ---------------- 256x128 full-fill GEMM for the projection (f32 out) ----------------
// grid = 16x16 = 256 blocks = exactly 1/CU.
__global__ __launch_bounds__(512, 1) void gemm_pn(const bf16* __restrict__ A,
                                                  const bf16* __restrict__ Bt,
                                                  float* __restrict__ C,
                                                  int M, int N, int K) {
    __shared__ __align__(16) bf16 smem[49152];  // A: [slot][mh][kb][128][32] at 0; B: [slot][kb][128][32] at +32768
    const int t = threadIdx.x, lane = t & 63, w = t >> 6;
    const int lr = lane & 15, quad = lane >> 4;
    const int nN = N >> 7;
    const int nwg = gridDim.x, chunk = nwg >> 3;
    const int bid = blockIdx.x;
    const int lid = (bid & 7) * chunk + (bid >> 3);   // XCD-contiguous
    const int m0 = (lid / nN) << 8, n0 = (lid % nN) << 7;
    const int mh_w = w >> 2;            // wave's A half (0/1)
    const int wn = (w & 3) << 5;        // wave's 32-wide N slice within the 128 tile
    const int nK = K >> 6;              // K-steps of 64

    const int ld0 = w * 2;
    const int lrow = lane >> 2;                        // 0..15
    const int csrc = (lane & 3) ^ ((lane >> 3) & 3);   // source col8 involution (2-bit)
    const int swz = (lr >> 1) & 3;                     // read-side involution (2-bit)

    auto stA = [&](int ts, int mh) {
        if (ts < nK) {
            bf16* db = smem + (ts & 1) * 16384 + mh * 8192;
            const bf16* sp = A + (size_t)(m0 + mh * 128) * K + ts * 64;
#pragma unroll
            for (int i = 0; i < 2; i++) {
                const int ldi = ld0 + i, kb = ldi >> 3, rg = ldi & 7;
                gl_lds16(sp + (size_t)(rg * 16 + lrow) * K + kb * 32 + csrc * 8,
                         db + kb * 4096 + rg * 512);
            }
        }
    };
    auto stB1 = [&](int ts) {  // whole 128-row B tile (16 KB)
        if (ts < nK) {
            bf16* db = smem + 32768 + (ts & 1) * 8192;
            const bf16* sp = Bt + (size_t)n0 * K + ts * 64;
#pragma unroll
            for (int i = 0; i < 2; i++) {
                const int ldi = ld0 + i, kb = ldi >> 3, rg = ldi & 7;
                gl_lds16(sp + (size_t)(rg * 16 + lrow) * K + kb * 32 + csrc * 8,
                         db + kb * 4096 + rg * 512);
            }
        }
    };

    f32x4 acc[8][2];
#pragma unroll
    for (int i = 0; i < 8; i++)
#pragma unroll
        for (int j = 0; j < 2; j++) acc[i][j] = (f32x4){0.f, 0.f, 0.f, 0.f};
    bf16x8 af[8], bf1[4];

    auto rdA = [&](int s, int fi0) {
        const bf16* bp = smem + s * 16384 + mh_w * 8192;
#pragma unroll
        for (int f = 0; f < 4; f++)
#pragma unroll
            for (int ks = 0; ks < 2; ks++)
                af[f * 2 + ks] = *(const bf16x8*)(bp + ks * 4096 +
                                                  ((fi0 + f) * 16 + lr) * 32 + (quad ^ swz) * 8);
    };
    auto rdB1 = [&](int s) {
        const bf16* bp = smem + 32768 + s * 8192;
#pragma unroll
        for (int f = 0; f < 2; f++)
#pragma unroll
            for (int ks = 0; ks < 2; ks++)
                bf1[f * 2 + ks] = *(const bf16x8*)(bp + ks * 4096 +
                                                   (wn + f * 16 + lr) * 32 + (quad ^ swz) * 8);
    };
    auto mm8 = [&](int fi0, int ks) {  // 8 independent MFMA (each acc touched once)
        __builtin_amdgcn_s_setprio(1);
#pragma unroll
        for (int f = 0; f < 4; f++)
#pragma unroll
            for (int g = 0; g < 2; g++)
                acc[fi0 + f][g] = __builtin_amdgcn_mfma_f32_16x16x32_bf16(
                    af[f * 2 + ks], bf1[g * 2 + ks], acc[fi0 + f][g], 0, 0, 0);
        __builtin_amdgcn_s_setprio(0);
    };

    // prologue: stage step 0, drain
    stA(0, 0); stA(0, 1); stB1(0);
    asm volatile("s_waitcnt vmcnt(0)" ::: "memory");
    bar();

    for (int ts = 0; ts < nK; ++ts) {
        const int s = ts & 1;
        // q0: A-frags fi0-3 + all B-frags ; stage A(t+1,0)
        rdA(s, 0); rdB1(s);
        stA(ts + 1, 0);
        bar();
        mm8(0, 0);
        bar();
        // q1: stage A(t+1,1) + B(t+1)
        stA(ts + 1, 1);
        stB1(ts + 1);
        bar();
        mm8(0, 1);
        bar();
        // q2: A-frags fi4-7
        rdA(s, 4);
        bar();
        mm8(4, 0);
        bar();
        // q3: register-only MFMA, then drain staged loads (issued >=2 phases ago)
        mm8(4, 1);
        asm volatile("s_waitcnt vmcnt(0)" ::: "memory");
        bar();
    }
    // epilogue: f32 stores, lanes lr contiguous in n
#pragma unroll
    for (int fi = 0; fi < 8; fi++) {
        const int m = m0 + mh_w * 128 + fi * 16 + quad * 4;
#pragma unroll
        for (int fj = 0; fj < 2; fj++) {
            const int n = n0 + wn + fj * 16 + lr;
#pragma unroll
            for (int r = 0; r < 4; r++)
                C[(size_t)(m + r) * N + n] = acc[fi][fj][r];
        }
    }
}

// ---------------- RoPE + RMSNorm; K and V written in MFMA-tiled layouts ----------------
// K: [(b,kvh)][dchunk=d>>3 (16)][s (2048)][d&7 (8)]
// V (sigma-permuted for flash's shuffle-free P^T fragments):
//   [(b,kvh)][gi = (s>>5)*4 + ((s&15)>>2) (256)][d (128)][el = ((s>>4)&1)*4 + (s&3) (8)]
__global__ __launch_bounds__(256) void rope_rms(const bf16* __restrict__ qkv,
                                                const float* __restrict__ qw,
                                                const float* __restrict__ kw,
                                                bf16* __restrict__ qb,
                                                bf16* __restrict__ kb,
                                                bf16* __restrict__ vt) {
    const int tok = blockIdx.x;
    const int b = tok >> 11, s = tok & (S_LEN - 1);
    const int lane = threadIdx.x & 63, w = threadIdx.x >> 6;
    const bf16* row = qkv + (size_t)tok * 3072;
    const float inv = expf(-(float)lane * (9.210340371976184f / 64.f));
    const float ang = (float)s * inv;
    float s_, c_;
    sincosf(ang, &s_, &c_);
    const float wq1 = qw[lane], wq2 = qw[lane + 64];
    const float wk1 = kw[lane], wk2 = kw[lane + 64];
    for (int u = w; u < 24; u += 4) {
        if (u < 16) {  // Q head: row-major [b,h][s][d]
            const float x1 = (float)row[u * 128 + lane], x2 = (float)row[u * 128 + 64 + lane];
            float y1 = x1 * c_ - x2 * s_;
            float y2 = x2 * c_ + x1 * s_;
            float ss = y1 * y1 + y2 * y2;
#pragma unroll
            for (int m = 1; m < 64; m <<= 1) ss += __shfl_xor(ss, m);
            const float r = rsqrtf(ss * (1.f / 128.f) + 1e-6f);
            size_t o = ((size_t)(b * NH + u) * S_LEN + s) * HD;
            qb[o + lane]      = (bf16)(y1 * r * wq1);
            qb[o + 64 + lane] = (bf16)(y2 * r * wq2);
        } else if (u < 20) {  // K head: tiled
            const int kh = u - 16;
            const float x1 = (float)row[2048 + kh * 128 + lane], x2 = (float)row[2048 + kh * 128 + 64 + lane];
            float y1 = x1 * c_ - x2 * s_;
            float y2 = x2 * c_ + x1 * s_;
            float ss = y1 * y1 + y2 * y2;
#pragma unroll
            for (int m = 1; m < 64; m <<= 1) ss += __shfl_xor(ss, m);
            const float r = rsqrtf(ss * (1.f / 128.f) + 1e-6f);
            size_t base = (size_t)(b * NKV + kh) * 16 * 16384;
            kb[base + (size_t)(lane >> 3) * 16384 + s * 8 + (lane & 7)]       = (bf16)(y1 * r * wk1);
            kb[base + (size_t)(8 + (lane >> 3)) * 16384 + s * 8 + (lane & 7)] = (bf16)(y2 * r * wk2);
        } else {  // V head: sigma-permuted tiled cast
            const int vh = u - 20;
            const float x1 = (float)row[2560 + vh * 128 + lane], x2 = (float)row[2560 + vh * 128 + 64 + lane];
            const int m = s & 31;
            const int gi = (s >> 5) * 4 + ((m & 15) >> 2);
            const int el = ((m >> 4) << 2) | (m & 3);
            size_t base = ((size_t)(b * NKV + vh) * 256 + gi) * 1024 + el;
            vt[base + (size_t)lane * 8]        = (bf16)x1;
            vt[base + (size_t)(lane + 64) * 8] = (bf16)x2;
        }
    }
}

// ---------------- flash attention v10 (causal, GQA, split-KV, 8-wave blocks) ----------------
__global__ __launch_bounds__(512, 4) void flash(const bf16* __restrict__ qg,
                                                const bf16* __restrict__ kg,
                                                const bf16* __restrict__ vg,
                                                bf16* __restrict__ attn,
                                                float* __restrict__ part_o,
                                                float* __restrict__ part_l) {
    // work list, descending tile count (9:20, 8:18, 15c:16, 7:16, 14c:15, ...)
    static const unsigned char QT[22] = {9,8,15,15,7,14,14,13,13,6,12,12,11,11,5,10,10,4,3,2,1,0};
    static const unsigned char CK[22] = {2,2,0,1,2,0,1,0,1,2,0,1,0,1,2,0,1,2,2,2,2,2};
    const int idx = blockIdx.x;
    const int g = idx >> 5, hb = idx & 31;
    const int qt = QT[g], ck = CK[g];
    const int h = hb & 15, b = hb >> 4;
    const int kvh = h >> 2;
    const int ktBeg = (ck == 1) ? (qt + 1) : 0;
    const int ktEnd = (ck == 0) ? (qt + 1) : (2 * qt + 2);
    const bf16* qh = qg + (size_t)(b * NH + h) * S_LEN * HD;
    const bf16* kh = kg + (size_t)(b * NKV + kvh) * (16 * 16384);
    const bf16* vh = vg + (size_t)(b * NKV + kvh) * (256 * 1024);
    __shared__ __align__(16) bf16 Ks[2][16 * 512];  // [buf][dchunk16][key64][8]  32 KB
    __shared__ __align__(16) bf16 Vs[2][8 * 1024];  // [buf][chunk8][d128][el8]   32 KB
    const int t = threadIdx.x, lane = t & 63, w = t >> 6, lr = lane & 15, quad = lane >> 4;
    const int row0 = qt * 128 + w * 16;             // this wave's 16 q-rows
    bf16x8 qf[4];
#pragma unroll
    for (int c = 0; c < 4; c++)
        qf[c] = *(const bf16x8*)(qh + (size_t)(row0 + lr) * HD + c * 32 + quad * 8);
    f32x4 o[8];
    f32x4 lacc = (f32x4){0.f, 0.f, 0.f, 0.f};
#pragma unroll
    for (int j = 0; j < 8; j++) o[j] = (f32x4){0.f, 0.f, 0.f, 0.f};
    const bf16 one = (bf16)1.0f;
    const bf16x8 ones8 = {one, one, one, one, one, one, one, one};
    const float C1 = 0.12751744f;    // (1/sqrt(128)) * log2(e)
    const float C2 = -17.3123405f;   // -12 * log2(e)   (fixed max M=12 > sqrt(128))

    // loop-invariant staging bases: K 2 dchunks/wave, V 1 chunk/wave (x8 waves)
    const bf16* kp[2];
#pragma unroll
    for (int i = 0; i < 2; i++) kp[i] = kh + (size_t)(w * 2 + i) * 16384 + lane * 8;
    const bf16* vp = vh + (size_t)w * 1024 + lane * 8;

    auto stage = [&](int kt_, int bi) {  // K+V tile kt_ -> buffers [bi]
        const size_t kb8 = (size_t)kt_ * 512;
#pragma unroll
        for (int i = 0; i < 2; i++)
            gl_lds16(kp[i] + kb8, &Ks[bi][(w * 2 + i) * 512]);
        const size_t vb = (size_t)kt_ * 8192;
        gl_lds16(vp + vb, &Vs[bi][w * 1024]);
        gl_lds16(vp + vb + 512, &Vs[bi][w * 1024 + 512]);
    };

    stage(ktBeg, 0);
    __syncthreads();
    int cur = 0;

    for (int kt = ktBeg; kt < ktEnd; ++kt) {
        const int kbase = kt * 64;
        if (kt + 1 < ktEnd) stage(kt + 1, cur ^ 1);  // prefetch; lands during this tile's compute
        // ---- QK^T (swapped): sacc[n] = S^T tile, col=lr=qrow, row=quad*4+r=key ----
        f32x4 sacc[4];
#pragma unroll
        for (int n = 0; n < 4; n++) sacc[n] = (f32x4){0.f, 0.f, 0.f, 0.f};
        __builtin_amdgcn_s_setprio(1);
#pragma unroll
        for (int c = 0; c < 4; c++)
#pragma unroll
            for (int n = 0; n < 4; n++) {
                bf16x8 kf = *(const bf16x8*)&Ks[cur][(c * 4 + quad) * 512 + (n * 16 + lr) * 8];
                sacc[n] = __builtin_amdgcn_mfma_f32_16x16x32_bf16(kf, qf[c], sacc[n], 0, 0, 0);
            }
        __builtin_amdgcn_s_setprio(0);
        // ---- fixed-max softmax -> P^T B-fragments via v_cvt_pk_bf16_f32 (T12) ----
        const bool diag = (kt >= 2 * qt);
        u32 pw[8];  // [(n>>1)*4 + (n&1)*2 + j] — compile-time indices
        {
            const int qrow = row0 + lr;
#pragma unroll
            for (int n = 0; n < 4; n++) {
                float e0, e1, e2, e3;
                {
                    float ev0 = exp2f(fmaf(sacc[n][0], C1, C2));
                    float ev1 = exp2f(fmaf(sacc[n][1], C1, C2));
                    float ev2 = exp2f(fmaf(sacc[n][2], C1, C2));
                    float ev3 = exp2f(fmaf(sacc[n][3], C1, C2));
                    if (diag) {
                        const int key = kbase + n * 16 + quad * 4;
                        ev0 = (key + 0 <= qrow) ? ev0 : 0.f;
                        ev1 = (key + 1 <= qrow) ? ev1 : 0.f;
                        ev2 = (key + 2 <= qrow) ? ev2 : 0.f;
                        ev3 = (key + 3 <= qrow) ? ev3 : 0.f;
                    }
                    e0 = ev0; e1 = ev1; e2 = ev2; e3 = ev3;
                }
                asm("v_cvt_pk_bf16_f32 %0, %1, %2"
                    : "=v"(pw[(n >> 1) * 4 + (n & 1) * 2 + 0]) : "v"(e0), "v"(e1));
                asm("v_cvt_pk_bf16_f32 %0, %1, %2"
                    : "=v"(pw[(n >> 1) * 4 + (n & 1) * 2 + 1]) : "v"(e2), "v"(e3));
            }
        }
        // ---- PV: O^T += V^T * P^T ; l via all-ones A-frag ----
        __builtin_amdgcn_s_setprio(1);
#pragma unroll
        for (int k2 = 0; k2 < 2; k2++) {
            const bf16x8 p0 = *(const bf16x8*)&pw[k2 * 4];
#pragma unroll
            for (int j = 0; j < 8; j++) {
                bf16x8 vf = *(const bf16x8*)&Vs[cur][(k2 * 4 + quad) * 1024 + (j * 16 + lr) * 8];
                o[j] = __builtin_amdgcn_mfma_f32_16x16x32_bf16(vf, p0, o[j], 0, 0, 0);
            }
            lacc = __builtin_amdgcn_mfma_f32_16x16x32_bf16(ones8, p0, lacc, 0, 0, 0);
        }
        __builtin_amdgcn_s_setprio(0);
        __syncthreads();  // drains stage(kt+1) (issued a full tile ago) + publishes buffers
        cur ^= 1;
    }
    // epilogue
    if (ck == 2) {  // direct: normalize, bf16x4 stores
        const float inv = 1.0f / lacc[0];
        const int qrow = row0 + lr;
        bf16* dst = attn + ((size_t)(b * S_LEN) + qrow) * (NH * HD) + h * HD + quad * 4;
#pragma unroll
        for (int j = 0; j < 8; j++) {
            bf16x4 st = { (bf16)(o[j][0] * inv), (bf16)(o[j][1] * inv),
                          (bf16)(o[j][2] * inv), (bf16)(o[j][3] * inv) };
            *(bf16x4*)(dst + j * 16) = st;
        }
    } else {  // partial: unnormalized f32 O + l
        const int slot = ((b * NH + h) * 6 + (qt - 10)) * 2 + ck;
        float* po = part_o + (size_t)slot * 16384;
        const int row = w * 16 + lr;
#pragma unroll
        for (int j = 0; j < 8; j++) {
            float4 st = { o[j][0], o[j][1], o[j][2], o[j][3] };
            *(float4*)(po + row * 128 + j * 16 + quad * 4) = st;
        }
        if (quad == 0) part_l[slot * 128 + row] = lacc[0];
    }
}

// ---------------- combine split-KV partials, normalize, write attn ----------------
// grid = 192 blocks: one per (b,h,qt in 10..15); 256 threads.
__global__ __launch_bounds__(256) void reduce_attn(const float* __restrict__ part_o,
                                                   const float* __restrict__ part_l,
                                                   bf16* __restrict__ attn) {
    const int blk = blockIdx.x;              // = (b*16+h)*6 + (qt-10)
    const int qt = (blk % 6) + 10;
    const int h = (blk / 6) & 15, b = blk / 96;
    const float* p0 = part_o + (size_t)(blk * 2 + 0) * 16384;
    const float* p1 = part_o + (size_t)(blk * 2 + 1) * 16384;
    const float* l0 = part_l + (blk * 2 + 0) * 128;
    const float* l1 = part_l + (blk * 2 + 1) * 128;
    const int t = threadIdx.x;
#pragma unroll
    for (int it = 0; it < 16; it++) {
        const int idx = it * 256 + t;        // f32x4 id, 4096 total
        const int row = idx >> 5, d4 = idx & 31;
        float4 a = ((const float4*)p0)[idx];
        float4 c = ((const float4*)p1)[idx];
        const float inv = 1.0f / (l0[row] + l1[row]);
        bf16x4 ov = { (bf16)((a.x + c.x) * inv), (bf16)((a.y + c.y) * inv),
                      (bf16)((a.z + c.z) * inv), (bf16)((a.w + c.w) * inv) };
        *(bf16x4*)(attn + ((size_t)(b * S_LEN) + qt * 128 + row) * (NH * HD) + h * HD + d4 * 4) = ov;
    }
}

extern "C" void kernel_launch(void* const* d_in, const int* in_sizes, int n_in,
                              void* d_out, int out_size, void* d_ws, size_t ws_size,
                              hipStream_t stream) {
    (void)in_sizes; (void)n_in; (void)out_size; (void)ws_size;
    const float* hs  = (const float*)d_in[0];
    const float* wq  = (const float*)d_in[1];
    const float* wk  = (const float*)d_in[2];
    const float* wv  = (const float*)d_in[3];
    const float* wo  = (const float*)d_in[4];
    const float* qnw = (const float*)d_in[5];
    const float* knw = (const float*)d_in[6];
    float* out = (float*)d_out;

    char* ws = (char*)d_ws;
    size_t off = 0;
    auto alloc = [&](size_t bytes) {
        void* p = ws + off;
        off += (bytes + 255) & ~(size_t)255;
        return p;
    };
    // NOTE: hs_bf / wqkv_bf / wo_bf must stay contiguous (cast_all writes them
    // as one flat region).
    bf16* hs_bf   = (bf16*)alloc((size_t)4096 * 2048 * 2);
    bf16* wqkv_bf = (bf16*)alloc((size_t)3072 * 2048 * 2);
    bf16* wo_bf   = (bf16*)alloc((size_t)2048 * 2048 * 2);
    bf16* qkv_bf  = (bf16*)alloc((size_t)4096 * 3072 * 2);
    bf16* q_bf    = (bf16*)alloc((size_t)B_DIM * NH * S_LEN * HD * 2);
    bf16* k_bf    = (bf16*)alloc((size_t)B_DIM * NKV * S_LEN * HD * 2);
    bf16* vt_bf   = (bf16*)alloc((size_t)B_DIM * NKV * S_LEN * HD * 2);
    bf16* at_bf   = (bf16*)alloc((size_t)4096 * 2048 * 2);

    // split-KV partials alias the hs_bf+wqkv_bf region (29.36 MB, free once the
    // QKV GEMM has consumed it; flash runs strictly after). 384 slots:
    // part_o 384*16384*4 = 25.17 MB, part_l 384*128*4 = 196 KB.
    float* part_o = (float*)hs_bf;
    float* part_l = (float*)((char*)hs_bf + (size_t)384 * 16384 * 4);

    cast_all<<<18432, 256, 0, stream>>>(hs, wq, wk, wv, wo, hs_bf);
    gemm_qkv<<<dim3(256), 512, 0, stream>>>(hs_bf, wqkv_bf, qkv_bf, 4096, 3072, 2048);
    rope_rms<<<4096, 256, 0, stream>>>(qkv_bf, qnw, knw, q_bf, k_bf, vt_bf);
    flash<<<dim3(704), 512, 0, stream>>>(q_bf, k_bf, vt_bf, at_bf, part_o, part_l);
    reduce_attn<<<dim3(192), 256, 0, stream>>>(part_o, part_l, at_bf);
    gemm_pn<<<dim3(256), 512, 0, stream>>>(at_bf, wo_bf, out, 4096, 2048, 2048);
}